// Round 4
// baseline (340.048 us; speedup 1.0000x reference)
//
#include <hip/hip_runtime.h>

typedef __attribute__((ext_vector_type(4))) float f32x4;
typedef __attribute__((ext_vector_type(8))) short bf16x8;

__device__ __forceinline__ unsigned short f2bf(float f) {
  unsigned int u = __builtin_bit_cast(unsigned int, f);
  u += 0x7FFFu + ((u >> 16) & 1u);   // RTNE
  return (unsigned short)(u >> 16);
}

// ---- K0a: P[b][h] = b_attn[h] + dot(W_attn[h, 0:512], hidden[b, :])
__global__ __launch_bounds__(256) void k_prep_p(
    const float* __restrict__ hidden, const float* __restrict__ W,
    const float* __restrict__ bias, float* __restrict__ P) {
  __shared__ float hsh[512];
  const int b = blockIdx.x;
  for (int i = threadIdx.x; i < 512; i += 256) hsh[i] = hidden[b * 512 + i];
  __syncthreads();
  for (int h = threadIdx.x; h < 512; h += 256) {
    const float* wr = W + (long)h * 1536;
    float s = 0.f;
#pragma unroll 4
    for (int f = 0; f < 512; f += 4) {
      float4 wv = *reinterpret_cast<const float4*>(wr + f);
      s += wv.x * hsh[f] + wv.y * hsh[f + 1] + wv.z * hsh[f + 2] + wv.w * hsh[f + 3];
    }
    P[b * 512 + h] = bias[h] + s;
  }
}

// ---- K0b: W2t[kb][h][kk] = bf16(W_attn[h][512 + kb*32 + kk]),  kb<32, h<512, kk<32
__global__ __launch_bounds__(256) void k_prep_w(
    const float* __restrict__ W, unsigned short* __restrict__ W2t) {
  const int id = blockIdx.x * 256 + threadIdx.x;  // 65536 threads, 8 elems each
  const int kk8 = (id & 3) * 8;
  const int h = (id >> 2) & 511;
  const int kb = id >> 11;
  const float* src = W + (long)h * 1536 + 512 + kb * 32 + kk8;
  float4 a = *reinterpret_cast<const float4*>(src);
  float4 c = *reinterpret_cast<const float4*>(src + 4);
  union { unsigned short u[8]; bf16x8 v; } o;
  o.u[0] = f2bf(a.x); o.u[1] = f2bf(a.y); o.u[2] = f2bf(a.z); o.u[3] = f2bf(a.w);
  o.u[4] = f2bf(c.x); o.u[5] = f2bf(c.y); o.u[6] = f2bf(c.z); o.u[7] = f2bf(c.w);
  *reinterpret_cast<bf16x8*>(W2t + (long)kb * 16384 + h * 32 + kk8) = o.v;
}

// ---- K1: fused GEMM + tanh + v-reduce -> logits partials
// 2048 blocks x 256 thr (4 waves, 1M x 4N). BM=64, BN=256 (ntile 0/1), K=1024.
// NO LDS staging, NO K-loop barriers: A-fragments loaded straight from enc
// (f32, full-line coalesced per kg-quad), converted to bf16 in registers.
// B from L2-resident repacked W2t. XCD-pair mapping puts the two ntiles of an
// mtile on the same XCD, adjacent in its dispatch stream (A shared via L2).
__global__ __launch_bounds__(256, 3) void k_main(
    const float* __restrict__ enc, const short* __restrict__ W2t,
    const float* __restrict__ P, const float* __restrict__ v,
    float* __restrict__ logits_part) {
  __shared__ float attred[64][4];

  const int tid = threadIdx.x;
  const int lane = tid & 63;
  const int wc = tid >> 6;              // 4 waves, each owns 64 N-cols
  const int hl = lane & 15, kg = lane >> 4;

  // bijective XCD-pair swizzle: 2048 = 8 xcd * 256; pair (ntile 0/1) adjacent
  const int bid = blockIdx.x;
  const int xcd = bid & 7, idx = bid >> 3;      // idx in 0..255
  const int mtile = xcd * 128 + (idx >> 1);     // 0..1023
  const int ntile = idx & 1;
  const long rowbase = (long)mtile * 64;
  const int colbase = ntile * 256;
  const int b = (int)(rowbase >> 12);           // 64 | 4096

  // A: row = rowbase + mi*16 + hl, k-offset = kb*32 + kg*8  (8 consecutive f32)
  const float4* ap[4];
#pragma unroll
  for (int mi = 0; mi < 4; ++mi)
    ap[mi] = reinterpret_cast<const float4*>(enc + (rowbase + mi * 16 + hl) * 1024 +
                                             kg * 8);
  // B: h = colbase + wc*64 + ni*16 + hl; elem = kb*16384 + h*32 + kg*8
  const short* bp = W2t + (colbase + wc * 64 + hl) * 32 + kg * 8;

  f32x4 acc[4][4];
#pragma unroll
  for (int mi = 0; mi < 4; ++mi)
#pragma unroll
    for (int ni = 0; ni < 4; ++ni) acc[mi][ni] = (f32x4){0.f, 0.f, 0.f, 0.f};

#pragma unroll 4
  for (int kb = 0; kb < 32; ++kb) {
    const short* bkb = bp + kb * 16384;
    bf16x8 bf[4];
#pragma unroll
    for (int ni = 0; ni < 4; ++ni)
      bf[ni] = *reinterpret_cast<const bf16x8*>(bkb + ni * 512);

    bf16x8 af[4];
#pragma unroll
    for (int mi = 0; mi < 4; ++mi) {
      float4 lo = ap[mi][kb * 8];
      float4 hi = ap[mi][kb * 8 + 1];
      union { __bf16 h[8]; bf16x8 s; } u;
      u.h[0] = (__bf16)lo.x; u.h[1] = (__bf16)lo.y;
      u.h[2] = (__bf16)lo.z; u.h[3] = (__bf16)lo.w;
      u.h[4] = (__bf16)hi.x; u.h[5] = (__bf16)hi.y;
      u.h[6] = (__bf16)hi.z; u.h[7] = (__bf16)hi.w;
      af[mi] = u.s;
    }

#pragma unroll
    for (int mi = 0; mi < 4; ++mi)
#pragma unroll
      for (int ni = 0; ni < 4; ++ni)
        acc[mi][ni] = __builtin_amdgcn_mfma_f32_16x16x32_bf16(af[mi], bf[ni],
                                                              acc[mi][ni], 0, 0, 0);
  }

  // epilogue: x = acc + P[b][h]; part += v[h]*tanh(x); reduce hl, then wc
  float part[4][4];
#pragma unroll
  for (int mi = 0; mi < 4; ++mi)
#pragma unroll
    for (int r = 0; r < 4; ++r) part[mi][r] = 0.f;

#pragma unroll
  for (int ni = 0; ni < 4; ++ni) {
    const int h = colbase + wc * 64 + ni * 16 + hl;
    const float ph = P[b * 512 + h];
    const float vh = v[h];
#pragma unroll
    for (int mi = 0; mi < 4; ++mi)
#pragma unroll
      for (int r = 0; r < 4; ++r) {
        float x = acc[mi][ni][r] + ph;
        float e = __expf(2.f * x);
        part[mi][r] += vh * (1.f - 2.f * __frcp_rn(e + 1.f));
      }
  }
#pragma unroll
  for (int off = 1; off < 16; off <<= 1)
#pragma unroll
    for (int mi = 0; mi < 4; ++mi)
#pragma unroll
      for (int r = 0; r < 4; ++r)
        part[mi][r] += __shfl_xor(part[mi][r], off, 16);

  if (hl == 0) {
#pragma unroll
    for (int mi = 0; mi < 4; ++mi)
#pragma unroll
      for (int r = 0; r < 4; ++r)
        attred[mi * 16 + kg * 4 + r][wc] = part[mi][r];
  }
  __syncthreads();
  if (tid < 64)
    logits_part[ntile * 65536 + rowbase + tid] =
        attred[tid][0] + attred[tid][1] + attred[tid][2] + attred[tid][3];
}

// ---- K2: softmax over S=4096 per batch row; input = sum of the 2 h-partials
__global__ __launch_bounds__(256) void k_softmax(
    const float* __restrict__ logits_part, float* __restrict__ out) {
  const int b = blockIdx.x;
  const int t = threadIdx.x;
  const int wid = t >> 6, lane = t & 63;
  const float* L0 = logits_part + b * 4096;
  const float* L1 = logits_part + 65536 + b * 4096;
  __shared__ float rmax[4], rsum[4];
  float lv[16];
  float m = -1e30f;
#pragma unroll
  for (int i = 0; i < 16; ++i) {
    lv[i] = L0[t + i * 256] + L1[t + i * 256];
    m = fmaxf(m, lv[i]);
  }
#pragma unroll
  for (int off = 32; off >= 1; off >>= 1) m = fmaxf(m, __shfl_xor(m, off));
  if (lane == 0) rmax[wid] = m;
  __syncthreads();
  m = fmaxf(fmaxf(rmax[0], rmax[1]), fmaxf(rmax[2], rmax[3]));
  float s = 0.f;
#pragma unroll
  for (int i = 0; i < 16; ++i) {
    lv[i] = __expf(lv[i] - m);
    s += lv[i];
  }
#pragma unroll
  for (int off = 32; off >= 1; off >>= 1) s += __shfl_xor(s, off);
  if (lane == 0) rsum[wid] = s;
  __syncthreads();
  s = rsum[0] + rsum[1] + rsum[2] + rsum[3];
  float inv = 1.0f / s;
#pragma unroll
  for (int i = 0; i < 16; ++i) out[b * 4096 + t + i * 256] = lv[i] * inv;
}

extern "C" void kernel_launch(void* const* d_in, const int* in_sizes, int n_in,
                              void* d_out, int out_size, void* d_ws, size_t ws_size,
                              hipStream_t stream) {
  const float* hidden = (const float*)d_in[0];   // [16,512]
  const float* enc    = (const float*)d_in[1];   // [16,4096,1024]
  const float* W      = (const float*)d_in[2];   // [512,1536]
  const float* bias   = (const float*)d_in[3];   // [512]
  const float* v      = (const float*)d_in[4];   // [512]
  float* out = (float*)d_out;                    // [16,4096]

  char* ws = (char*)d_ws;
  float* P = (float*)ws;                                       // 32 KB
  unsigned short* W2t = (unsigned short*)(ws + 32768);         // 1 MB
  float* logits_part = (float*)(ws + 32768 + 1048576);         // 2 x 256 KB

  k_prep_p<<<16, 256, 0, stream>>>(hidden, W, bias, P);
  k_prep_w<<<256, 256, 0, stream>>>(W, W2t);
  k_main<<<2048, 256, 0, stream>>>(enc, (const short*)W2t, P, v, logits_part);
  k_softmax<<<16, 256, 0, stream>>>(logits_part, out);
}

// Round 5
// 167.586 us; speedup vs baseline: 2.0291x; 2.0291x over previous
//
#include <hip/hip_runtime.h>

typedef __attribute__((ext_vector_type(4))) float f32x4;
typedef __attribute__((ext_vector_type(8))) short bf16x8;

typedef const __attribute__((address_space(1))) void* gptr_t;
typedef __attribute__((address_space(3))) void* lptr_t;
#define GLS16(g, l) __builtin_amdgcn_global_load_lds((gptr_t)(g), (lptr_t)(l), 16, 0, 0)

__device__ __forceinline__ unsigned short f2bf(float f) {
  unsigned int u = __builtin_bit_cast(unsigned int, f);
  u += 0x7FFFu + ((u >> 16) & 1u);   // RTNE
  return (unsigned short)(u >> 16);
}

// ---- K0a: P[b][h] = b_attn[h] + dot(W_attn[h, 0:512], hidden[b, :])
__global__ __launch_bounds__(256) void k_prep_p(
    const float* __restrict__ hidden, const float* __restrict__ W,
    const float* __restrict__ bias, float* __restrict__ P) {
  __shared__ float hsh[512];
  const int b = blockIdx.x;
  for (int i = threadIdx.x; i < 512; i += 256) hsh[i] = hidden[b * 512 + i];
  __syncthreads();
  for (int h = threadIdx.x; h < 512; h += 256) {
    const float* wr = W + (long)h * 1536;
    float s = 0.f;
#pragma unroll 4
    for (int f = 0; f < 512; f += 4) {
      float4 wv = *reinterpret_cast<const float4*>(wr + f);
      s += wv.x * hsh[f] + wv.y * hsh[f + 1] + wv.z * hsh[f + 2] + wv.w * hsh[f + 3];
    }
    P[b * 512 + h] = bias[h] + s;
  }
}

// ---- K0b: W2t[kb][h][kk] = bf16(W_attn[h][512 + kb*32 + kk]),  kb<32, h<512, kk<32
__global__ __launch_bounds__(256) void k_prep_w(
    const float* __restrict__ W, unsigned short* __restrict__ W2t) {
  const int id = blockIdx.x * 256 + threadIdx.x;  // 65536 threads, 8 elems each
  const int kk8 = (id & 3) * 8;
  const int h = (id >> 2) & 511;
  const int kb = id >> 11;
  const float* src = W + (long)h * 1536 + 512 + kb * 32 + kk8;
  float4 a = *reinterpret_cast<const float4*>(src);
  float4 c = *reinterpret_cast<const float4*>(src + 4);
  union { unsigned short u[8]; bf16x8 v; } o;
  o.u[0] = f2bf(a.x); o.u[1] = f2bf(a.y); o.u[2] = f2bf(a.z); o.u[3] = f2bf(a.w);
  o.u[4] = f2bf(c.x); o.u[5] = f2bf(c.y); o.u[6] = f2bf(c.z); o.u[7] = f2bf(c.w);
  *reinterpret_cast<bf16x8*>(W2t + (long)kb * 16384 + h * 32 + kk8) = o.v;
}

// ---- K1: fused GEMM + tanh + v-reduce -> logits partials (m97-style structure)
// 2048 blocks = 512 mtiles x 4 ntiles; 256 thr = 4 waves (2M x 2N), wave 64x64.
// BM=128 BN=128 BK=32. A staged f32 via global_load_lds (dbuf, XOR-swizzled
// source), converted bf16 on LDS read. B direct from L2-resident W2t.
__global__ __launch_bounds__(256, 3) void k_main(
    const float* __restrict__ enc, const short* __restrict__ W2t,
    const float* __restrict__ P, const float* __restrict__ v,
    float* __restrict__ logits_part) {
  __shared__ float As[2][4096];        // [buf][128 rows][32 k] f32, 2 x 16 KB
  __shared__ float attred[128][2];

  const int tid = threadIdx.x;
  const int lane = tid & 63;
  const int w = tid >> 6;               // 4 waves
  const int wr = w >> 1, wc = w & 1;    // 2M x 2N
  const int hl = lane & 15, kg = lane >> 4;

  // XCD swizzle: 4 ntile-sharers of an mtile adjacent on one XCD (bijective)
  const int bid = blockIdx.x;
  const int xcd = bid & 7, idx = bid >> 3;        // idx 0..255
  const int mtile = xcd * 64 + (idx >> 2);        // 0..511
  const int ntile = idx & 3;
  const long rowbase = (long)mtile * 128;
  const int colbase = ntile * 128;
  const int b = (int)(rowbase >> 12);             // 128 | 4096

  // ---- A staging (global_load_lds): per wave 4 issues, each 8 rows x 32 k.
  // LDS linear; global source chunk pre-swizzled: chunk = (lane&7)^(lane>>3).
  const int srow = lane >> 3;                      // 0..7 within 8-row group
  const int schunk = (lane & 7) ^ srow;            // XOR involution (row&7==srow)
  const float* gp0 = enc + (rowbase + 0 * 32 + w * 8 + srow) * 1024 + schunk * 4;
  const float* gp1 = enc + (rowbase + 1 * 32 + w * 8 + srow) * 1024 + schunk * 4;
  const float* gp2 = enc + (rowbase + 2 * 32 + w * 8 + srow) * 1024 + schunk * 4;
  const float* gp3 = enc + (rowbase + 3 * 32 + w * 8 + srow) * 1024 + schunk * 4;
  const int l0 = w * 256 + 0 * 1024;   // float offsets within a buffer
  const int l1 = w * 256 + 1 * 1024;
  const int l2 = w * 256 + 2 * 1024;
  const int l3 = w * 256 + 3 * 1024;

  // A-frag read: row = wr*64 + mi*16 + hl; slot0 = (kg*2)^(hl&7), slot1 = slot0^1
  const int s0 = ((kg << 1) ^ (hl & 7));
  // B: h = colbase + wc*64 + ni*16 + hl; elem = kb*16384 + h*32 + kg*8
  const short* bp = W2t + (colbase + wc * 64 + hl) * 32 + kg * 8;

  f32x4 acc[4][4];
#pragma unroll
  for (int mi = 0; mi < 4; ++mi)
#pragma unroll
    for (int ni = 0; ni < 4; ++ni) acc[mi][ni] = (f32x4){0.f, 0.f, 0.f, 0.f};

  // prologue: stage tile 0 into buffer 0
  GLS16(gp0, &As[0][l0]);
  GLS16(gp1, &As[0][l1]);
  GLS16(gp2, &As[0][l2]);
  GLS16(gp3, &As[0][l3]);
  __syncthreads();

#pragma unroll 2
  for (int kb = 0; kb < 32; ++kb) {
    const int cur = kb & 1;
    // B loads FIRST (oldest vmem this iter -> wait for B keeps prefetch in flight)
    const short* bkb = bp + kb * 16384;
    bf16x8 bf0 = *reinterpret_cast<const bf16x8*>(bkb);
    bf16x8 bf1 = *reinterpret_cast<const bf16x8*>(bkb + 512);
    bf16x8 bf2 = *reinterpret_cast<const bf16x8*>(bkb + 1024);
    bf16x8 bf3 = *reinterpret_cast<const bf16x8*>(bkb + 1536);
    // prefetch next A tile into other buffer (no data VGPRs needed)
    if (kb < 31) {
      const int koff = (kb + 1) * 32;
      GLS16(gp0 + koff, &As[cur ^ 1][l0]);
      GLS16(gp1 + koff, &As[cur ^ 1][l1]);
      GLS16(gp2 + koff, &As[cur ^ 1][l2]);
      GLS16(gp3 + koff, &As[cur ^ 1][l3]);
    }
    // A frags: ds_read f32 (swizzled slots) + cvt to bf16
    bf16x8 af[4];
#pragma unroll
    for (int mi = 0; mi < 4; ++mi) {
      const int ro = (wr * 64 + mi * 16 + hl) * 32;
      f32x4 lo = *reinterpret_cast<const f32x4*>(&As[cur][ro + s0 * 4]);
      f32x4 hi = *reinterpret_cast<const f32x4*>(&As[cur][ro + (s0 ^ 1) * 4]);
      union { __bf16 h[8]; bf16x8 s; } u;
      u.h[0] = (__bf16)lo[0]; u.h[1] = (__bf16)lo[1];
      u.h[2] = (__bf16)lo[2]; u.h[3] = (__bf16)lo[3];
      u.h[4] = (__bf16)hi[0]; u.h[5] = (__bf16)hi[1];
      u.h[6] = (__bf16)hi[2]; u.h[7] = (__bf16)hi[3];
      af[mi] = u.s;
    }
#pragma unroll
    for (int mi = 0; mi < 4; ++mi) {
      acc[mi][0] = __builtin_amdgcn_mfma_f32_16x16x32_bf16(af[mi], bf0, acc[mi][0], 0, 0, 0);
      acc[mi][1] = __builtin_amdgcn_mfma_f32_16x16x32_bf16(af[mi], bf1, acc[mi][1], 0, 0, 0);
      acc[mi][2] = __builtin_amdgcn_mfma_f32_16x16x32_bf16(af[mi], bf2, acc[mi][2], 0, 0, 0);
      acc[mi][3] = __builtin_amdgcn_mfma_f32_16x16x32_bf16(af[mi], bf3, acc[mi][3], 0, 0, 0);
    }
    __syncthreads();   // drains prefetch; next buffer ready, cur consumed
  }

  // epilogue: x = acc + P[b][h]; part += v[h]*tanh(x); reduce hl, then wc
  float part[4][4];
#pragma unroll
  for (int mi = 0; mi < 4; ++mi)
#pragma unroll
    for (int r = 0; r < 4; ++r) part[mi][r] = 0.f;

#pragma unroll
  for (int ni = 0; ni < 4; ++ni) {
    const int h = colbase + wc * 64 + ni * 16 + hl;
    const float ph = P[b * 512 + h];
    const float vh = v[h];
#pragma unroll
    for (int mi = 0; mi < 4; ++mi)
#pragma unroll
      for (int r = 0; r < 4; ++r) {
        float x = acc[mi][ni][r] + ph;
        float e = __expf(2.f * x);
        part[mi][r] += vh * (1.f - 2.f * __frcp_rn(e + 1.f));
      }
  }
#pragma unroll
  for (int off = 1; off < 16; off <<= 1)
#pragma unroll
    for (int mi = 0; mi < 4; ++mi)
#pragma unroll
      for (int r = 0; r < 4; ++r)
        part[mi][r] += __shfl_xor(part[mi][r], off, 16);

  if (hl == 0) {
#pragma unroll
    for (int mi = 0; mi < 4; ++mi)
#pragma unroll
      for (int r = 0; r < 4; ++r)
        attred[wr * 64 + mi * 16 + kg * 4 + r][wc] = part[mi][r];
  }
  __syncthreads();
  if (tid < 128)
    logits_part[ntile * 65536 + rowbase + tid] = attred[tid][0] + attred[tid][1];
}

// ---- K2: softmax over S=4096 per batch row; input = sum of 4 h-partials
__global__ __launch_bounds__(256) void k_softmax(
    const float* __restrict__ logits_part, float* __restrict__ out) {
  const int b = blockIdx.x;
  const int t = threadIdx.x;
  const int wid = t >> 6, lane = t & 63;
  const float* L0 = logits_part + b * 4096;
  const float* L1 = logits_part + 65536 + b * 4096;
  const float* L2 = logits_part + 131072 + b * 4096;
  const float* L3 = logits_part + 196608 + b * 4096;
  __shared__ float rmax[4], rsum[4];
  float lv[16];
  float m = -1e30f;
#pragma unroll
  for (int i = 0; i < 16; ++i) {
    const int j = t + i * 256;
    lv[i] = (L0[j] + L1[j]) + (L2[j] + L3[j]);
    m = fmaxf(m, lv[i]);
  }
#pragma unroll
  for (int off = 32; off >= 1; off >>= 1) m = fmaxf(m, __shfl_xor(m, off));
  if (lane == 0) rmax[wid] = m;
  __syncthreads();
  m = fmaxf(fmaxf(rmax[0], rmax[1]), fmaxf(rmax[2], rmax[3]));
  float s = 0.f;
#pragma unroll
  for (int i = 0; i < 16; ++i) {
    lv[i] = __expf(lv[i] - m);
    s += lv[i];
  }
#pragma unroll
  for (int off = 32; off >= 1; off >>= 1) s += __shfl_xor(s, off);
  if (lane == 0) rsum[wid] = s;
  __syncthreads();
  s = rsum[0] + rsum[1] + rsum[2] + rsum[3];
  float inv = 1.0f / s;
#pragma unroll
  for (int i = 0; i < 16; ++i) out[b * 4096 + t + i * 256] = lv[i] * inv;
}

extern "C" void kernel_launch(void* const* d_in, const int* in_sizes, int n_in,
                              void* d_out, int out_size, void* d_ws, size_t ws_size,
                              hipStream_t stream) {
  const float* hidden = (const float*)d_in[0];   // [16,512]
  const float* enc    = (const float*)d_in[1];   // [16,4096,1024]
  const float* W      = (const float*)d_in[2];   // [512,1536]
  const float* bias   = (const float*)d_in[3];   // [512]
  const float* v      = (const float*)d_in[4];   // [512]
  float* out = (float*)d_out;                    // [16,4096]

  char* ws = (char*)d_ws;
  float* P = (float*)ws;                                       // 32 KB
  unsigned short* W2t = (unsigned short*)(ws + 32768);         // 1 MB
  float* logits_part = (float*)(ws + 32768 + 1048576);         // 4 x 256 KB

  k_prep_p<<<16, 256, 0, stream>>>(hidden, W, bias, P);
  k_prep_w<<<256, 256, 0, stream>>>(W, W2t);
  k_main<<<2048, 256, 0, stream>>>(enc, (const short*)W2t, P, v, logits_part);
  k_softmax<<<16, 256, 0, stream>>>(logits_part, out);
}